// Round 1
// baseline (504.674 us; speedup 1.0000x reference)
//
#include <hip/hip_runtime.h>
#include <math.h>

#define B 4
#define S 2048
#define E 1024
#define H 64

// ---------------- wave (64-lane) reductions ----------------
__device__ inline float wave_max(float x) {
    #pragma unroll
    for (int o = 32; o > 0; o >>= 1) x = fmaxf(x, __shfl_xor(x, o));
    return x;
}
__device__ inline float wave_sum(float x) {
    #pragma unroll
    for (int o = 32; o > 0; o >>= 1) x += __shfl_xor(x, o);
    return x;
}

// ---------------- projections: q/k/v = x @ W + b ----------------
// block = 192 threads (3 waves). wave p in {0,1,2} handles projection p,
// lane = output column h. R=8 rows per block, E chunked through LDS.
#define RPB 8
#define EC 128

__global__ __launch_bounds__(192) void proj_kernel(
    const float* __restrict__ query, const float* __restrict__ key_,
    const float* __restrict__ value,
    const float* __restrict__ Wq, const float* __restrict__ bq,
    const float* __restrict__ Wk, const float* __restrict__ bk,
    const float* __restrict__ Wv, const float* __restrict__ bv,
    float* __restrict__ qo, float* __restrict__ ko, float* __restrict__ vo)
{
    __shared__ float4 x_lds[3][RPB][EC / 4];   // 12 KB

    const int t = threadIdx.x;
    const int p = t >> 6;        // wave index = projection
    const int h = t & 63;        // lane = output column
    const int bid = blockIdx.x;
    const int b  = bid / (S / RPB);
    const int s0 = (bid % (S / RPB)) * RPB;

    const float* xs[3] = {query, key_, value};
    const float* Ws[3] = {Wq, Wk, Wv};
    const float* bs[3] = {bq, bk, bv};
    float*       os[3] = {qo, ko, vo};

    const float* Wp = Ws[p];

    float acc[RPB];
    #pragma unroll
    for (int r = 0; r < RPB; r++) acc[r] = 0.f;

    for (int c = 0; c < E / EC; c++) {
        __syncthreads();
        // stage 3 x 8 x 128 floats = 768 float4, 4 per thread
        #pragma unroll
        for (int i = 0; i < 4; i++) {
            int f4 = t + 192 * i;          // 0..767
            int pp = f4 >> 8;              // 0..2
            int rr = (f4 >> 5) & 7;        // 0..7
            int eq = f4 & 31;              // 0..31
            x_lds[pp][rr][eq] =
                ((const float4*)(xs[pp] + (size_t)(b * S + s0 + rr) * E + c * EC))[eq];
        }
        __syncthreads();

        #pragma unroll 4
        for (int eq = 0; eq < EC / 4; eq++) {
            int e = c * EC + 4 * eq;
            // W is [E][H] row-major: coalesced across lanes, hot in L1/L2
            float w0 = Wp[(e + 0) * H + h];
            float w1 = Wp[(e + 1) * H + h];
            float w2 = Wp[(e + 2) * H + h];
            float w3 = Wp[(e + 3) * H + h];
            #pragma unroll
            for (int r = 0; r < RPB; r++) {
                float4 x4 = x_lds[p][r][eq];   // broadcast read
                acc[r] += x4.x * w0 + x4.y * w1 + x4.z * w2 + x4.w * w3;
            }
        }
    }

    const float bias = bs[p][h];
    float* op = os[p];
    #pragma unroll
    for (int r = 0; r < RPB; r++)
        op[(size_t)(b * S + s0 + r) * H + h] = acc[r] + bias;
}

// ---------------- flash attention (fp32, online softmax) ----------------
// block = 256 threads (4 waves). Wave g owns q-rows 4g..4g+3; lane = h (=64)
// for PV / = key j (=64) for scores. K tiles of 64 staged in LDS; V staged
// transposed so PV is float4 dots over j.
#define TQ 16
#define TK 64

__global__ __launch_bounds__(256) void attn_kernel(
    const float* __restrict__ qp, const float* __restrict__ kp,
    const float* __restrict__ vp, float* __restrict__ out)
{
    __shared__ float4 q_lds[TQ][H / 4];        // 4 KB
    __shared__ float4 k_lds[TK][17];           // 17.4 KB (stride-17 pad)
    __shared__ float4 vt_lds[TK][17];          // 17.4 KB, transposed [h][j]
    __shared__ float4 e_lds[TQ][TK / 4];       // 4 KB

    const int t = threadIdx.x;
    const int wave = t >> 6;
    const int lane = t & 63;
    const int bid = blockIdx.x;
    const int b  = bid / (S / TQ);
    const int s0 = (bid % (S / TQ)) * TQ;
    const int r0 = wave * 4;

    // stage q tile (16x64 floats = 256 float4, 1 per thread); covered by
    // the first loop-top barrier.
    {
        int r = t >> 4, hq = t & 15;
        q_lds[r][hq] = ((const float4*)(qp + (size_t)(b * S + s0 + r) * H))[hq];
    }

    float m[4], l[4], acc[4];
    #pragma unroll
    for (int i = 0; i < 4; i++) { m[i] = -INFINITY; l[i] = 0.f; acc[i] = 0.f; }

    for (int kt = 0; kt < S / TK; kt++) {
        __syncthreads();   // previous tile fully consumed (and q staged, kt=0)

        // ---- stage K tile: fully coalesced float4 ----
        const float* kbase = kp + (size_t)(b * S + kt * TK) * H;
        #pragma unroll
        for (int i = 0; i < 4; i++) {
            int f4 = t + 256 * i;
            int j = f4 >> 4, hq = f4 & 15;
            k_lds[j][hq] = ((const float4*)(kbase + j * H))[hq];
        }
        // ---- stage V tile transposed: vt[h][j] ----
        const float* vbase = vp + (size_t)(b * S + kt * TK) * H;
        float* vt = (float*)vt_lds;
        #pragma unroll
        for (int i = 0; i < 4; i++) {
            int hq = wave + 4 * i;     // wave-uniform column group
            int j  = lane;
            float4 vv = ((const float4*)(vbase + (size_t)j * H))[hq];
            vt[(4 * hq + 0) * 68 + j] = vv.x;
            vt[(4 * hq + 1) * 68 + j] = vv.y;
            vt[(4 * hq + 2) * 68 + j] = vv.z;
            vt[(4 * hq + 3) * 68 + j] = vv.w;
        }
        __syncthreads();

        // ---- scores: s[i] = q[r0+i] . k[lane] ----
        float s[4] = {0.f, 0.f, 0.f, 0.f};
        #pragma unroll
        for (int hq = 0; hq < H / 4; hq++) {
            float4 kk = k_lds[lane][hq];
            #pragma unroll
            for (int i = 0; i < 4; i++) {
                float4 qq = q_lds[r0 + i][hq];   // broadcast read
                s[i] += qq.x * kk.x + qq.y * kk.y + qq.z * kk.z + qq.w * kk.w;
            }
        }

        // ---- online softmax update ----
        float* e_f = (float*)e_lds;
        #pragma unroll
        for (int i = 0; i < 4; i++) {
            float mt = wave_max(s[i]);
            float mn = fmaxf(m[i], mt);
            float al = __expf(m[i] - mn);     // 0 when m = -inf
            float ei = __expf(s[i] - mn);
            float ls = wave_sum(ei);
            l[i] = l[i] * al + ls;
            acc[i] *= al;
            m[i] = mn;
            e_f[(r0 + i) * TK + lane] = ei;
        }
        __syncthreads();

        // ---- PV: acc[i] += sum_j e[r0+i][j] * v[j][lane] ----
        #pragma unroll
        for (int jq = 0; jq < TK / 4; jq++) {
            float4 vv = vt_lds[lane][jq];
            #pragma unroll
            for (int i = 0; i < 4; i++) {
                float4 ee = e_lds[r0 + i][jq];   // broadcast read
                acc[i] += ee.x * vv.x + ee.y * vv.y + ee.z * vv.z + ee.w * vv.w;
            }
        }
    }

    float* obase = out + (size_t)(b * S + s0) * H;
    #pragma unroll
    for (int i = 0; i < 4; i++)
        obase[(size_t)(r0 + i) * H + lane] = acc[i] / l[i];
}

extern "C" void kernel_launch(void* const* d_in, const int* in_sizes, int n_in,
                              void* d_out, int out_size, void* d_ws, size_t ws_size,
                              hipStream_t stream) {
    const float* query = (const float*)d_in[0];
    const float* key_  = (const float*)d_in[1];
    const float* value = (const float*)d_in[2];
    const float* Wq    = (const float*)d_in[3];
    const float* bq    = (const float*)d_in[4];
    const float* Wk    = (const float*)d_in[5];
    const float* bk    = (const float*)d_in[6];
    const float* Wv    = (const float*)d_in[7];
    const float* bv    = (const float*)d_in[8];
    float* out = (float*)d_out;

    // workspace: q,k,v projections, [B][S][H] fp32 each (2 MB apiece)
    float* qo = (float*)d_ws;
    float* ko = qo + (size_t)B * S * H;
    float* vo = ko + (size_t)B * S * H;

    proj_kernel<<<(B * S) / RPB, 192, 0, stream>>>(
        query, key_, value, Wq, bq, Wk, bk, Wv, bv, qo, ko, vo);

    attn_kernel<<<B * (S / TQ), 256, 0, stream>>>(qo, ko, vo, out);
}

// Round 2
// 170.946 us; speedup vs baseline: 2.9522x; 2.9522x over previous
//
#include <hip/hip_runtime.h>
#include <math.h>

#define B 4
#define S 2048
#define E 1024
#define H 64
#define BS (B*S)
#define LOG2E 1.44269504088896f
#define CINIT (-69.2493662f)   // -48 * log2(e): fixed softmax max in log2 domain

typedef float v4f __attribute__((ext_vector_type(4)));
typedef short v8s __attribute__((ext_vector_type(8)));
typedef unsigned short u16;
typedef u16 u16x8 __attribute__((ext_vector_type(8)));

#define MFMA(a,b,c) __builtin_amdgcn_mfma_f32_16x16x32_bf16(a,b,c,0,0,0)

// round-half-up fp32 -> bf16 (bias 2^-17, irrelevant here; 2 VALU ops)
__device__ inline u16 rh_bf16(float x){ return (u16)((__float_as_uint(x)+0x8000u)>>16); }

// ============================================================
// k0: W[E][H] fp32 -> transposed hi/lo bf16 planes Wt[p][h][e].
// p==0 (Wq) pre-scaled by log2(e) so scores land in log2 domain.
// ============================================================
__global__ __launch_bounds__(256) void wsetup_kernel(
    const float* __restrict__ Wq, const float* __restrict__ Wk,
    const float* __restrict__ Wv,
    u16* __restrict__ Wt_hi, u16* __restrict__ Wt_lo)
{
    __shared__ float wt[64][65];
    const int t  = threadIdx.x;
    const int p  = blockIdx.x >> 4;
    const int e0 = (blockIdx.x & 15) * 64;
    const float* Wsrc = (p==0) ? Wq : (p==1 ? Wk : Wv);
    const float scale = (p==0) ? LOG2E : 1.0f;

    #pragma unroll
    for (int i=0;i<16;i++){
        int e_l = i*4 + (t>>6);
        wt[e_l][t&63] = Wsrc[(size_t)(e0+e_l)*H + (t&63)] * scale;
    }
    __syncthreads();

    const int h = t>>2, e16 = (t&3)*16;
    u16 hi_a[16], lo_a[16];
    #pragma unroll
    for (int j=0;j<16;j++){
        float f = wt[e16+j][h];
        unsigned u = __float_as_uint(f);
        hi_a[j] = (u16)(u>>16);                       // truncation split
        float hif = __uint_as_float(u & 0xFFFF0000u);
        lo_a[j] = rh_bf16(f - hif);                   // residual to bf16
    }
    u16* dh = Wt_hi + (size_t)(p*64+h)*E + e0 + e16;
    u16* dl = Wt_lo + (size_t)(p*64+h)*E + e0 + e16;
    *(u16x8*)dh     = *(u16x8*)&hi_a[0];
    *(u16x8*)(dh+8) = *(u16x8*)&hi_a[8];
    *(u16x8*)dl     = *(u16x8*)&lo_a[0];
    *(u16x8*)(dl+8) = *(u16x8*)&lo_a[8];
}

// ============================================================
// k1: projections via MFMA with hi/lo 3-term products (~fp32 exact).
// block = 128 thr (2 waves, 16 rows each = 32 rows/block), one projection.
// outputs: q_hi/q_lo, k_hi/k_lo (bf16 split), v_bf (plain bf16).
// ============================================================
__global__ __launch_bounds__(128) void proj_kernel(
    const float* __restrict__ query, const float* __restrict__ key_,
    const float* __restrict__ value,
    const u16* __restrict__ Wt_hi, const u16* __restrict__ Wt_lo,
    const float* __restrict__ bq, const float* __restrict__ bk,
    const float* __restrict__ bv,
    u16* __restrict__ q_hi, u16* __restrict__ q_lo,
    u16* __restrict__ k_hi, u16* __restrict__ k_lo,
    u16* __restrict__ v_bf)
{
    __shared__ __align__(16) u16 xh[32][72], xl[32][72];   // x tile hi/lo
    __shared__ __align__(16) u16 wh[64][72], wl[64][72];   // W^T tile hi/lo

    const int t  = threadIdx.x;
    const int p  = blockIdx.x >> 8;           // 0..2
    const int r0 = (blockIdx.x & 255) * 32;   // global row base (flat [BS])
    const float* xp = (p==0) ? query : (p==1 ? key_ : value);
    const int wv = t>>6, lane = t&63, m = lane&15, quad = lane>>4;

    const int srow = t>>2, se16 = (t&3)*16;   // x staging coords
    const int swh  = t>>1, seo  = (t&1)*32;   // W staging coords

    v4f acc[4];
    #pragma unroll
    for (int nt=0;nt<4;nt++) acc[nt] = (v4f){0.f,0.f,0.f,0.f};

    for (int ec=0; ec<16; ec++){
        const int e0 = ec*64;
        __syncthreads();
        // ---- stage x chunk (32 rows x 64 e fp32), convert to hi/lo ----
        {
            const float* xr = xp + (size_t)(r0+srow)*E + e0 + se16;
            float4 aa[4];
            aa[0] = *(const float4*)(xr);
            aa[1] = *(const float4*)(xr+4);
            aa[2] = *(const float4*)(xr+8);
            aa[3] = *(const float4*)(xr+12);
            float fv[16];
            #pragma unroll
            for (int q4=0;q4<4;q4++){
                fv[q4*4+0]=aa[q4].x; fv[q4*4+1]=aa[q4].y;
                fv[q4*4+2]=aa[q4].z; fv[q4*4+3]=aa[q4].w;
            }
            u16 ha[16], la[16];
            #pragma unroll
            for (int j=0;j<16;j++){
                unsigned u = __float_as_uint(fv[j]);
                ha[j] = (u16)(u>>16);
                la[j] = rh_bf16(fv[j] - __uint_as_float(u & 0xFFFF0000u));
            }
            *(u16x8*)&xh[srow][se16]   = *(u16x8*)&ha[0];
            *(u16x8*)&xh[srow][se16+8] = *(u16x8*)&ha[8];
            *(u16x8*)&xl[srow][se16]   = *(u16x8*)&la[0];
            *(u16x8*)&xl[srow][se16+8] = *(u16x8*)&la[8];
        }
        // ---- stage W^T chunk (64 h x 64 e bf16 hi+lo) ----
        {
            const u16* sh = Wt_hi + (size_t)(p*64+swh)*E + e0 + seo;
            const u16* sl = Wt_lo + (size_t)(p*64+swh)*E + e0 + seo;
            #pragma unroll
            for (int i=0;i<4;i++){
                *(u16x8*)&wh[swh][seo + i*8] = *(const u16x8*)(sh + i*8);
                *(u16x8*)&wl[swh][seo + i*8] = *(const u16x8*)(sl + i*8);
            }
        }
        __syncthreads();

        // ---- MFMA: 3-term hi/lo, K=64 per chunk (2 sub-chunks of 32) ----
        v8s ah0 = *(v8s*)&xh[wv*16+m][quad*8];
        v8s ah1 = *(v8s*)&xh[wv*16+m][32+quad*8];
        v8s al0 = *(v8s*)&xl[wv*16+m][quad*8];
        v8s al1 = *(v8s*)&xl[wv*16+m][32+quad*8];
        #pragma unroll
        for (int nt=0;nt<4;nt++){
            v8s bh0 = *(v8s*)&wh[nt*16+m][quad*8];
            v8s bh1 = *(v8s*)&wh[nt*16+m][32+quad*8];
            v8s bl0 = *(v8s*)&wl[nt*16+m][quad*8];
            v8s bl1 = *(v8s*)&wl[nt*16+m][32+quad*8];
            v4f d = acc[nt];
            d = MFMA(ah0,bh0,d); d = MFMA(ah1,bh1,d);   // hi*hi
            d = MFMA(al0,bh0,d); d = MFMA(al1,bh1,d);   // lo*hi
            d = MFMA(ah0,bl0,d); d = MFMA(ah1,bl1,d);   // hi*lo
            acc[nt] = d;
        }
    }

    // ---- epilogue: +bias, hi/lo split store (or plain bf16 for v) ----
    const float* bp = (p==0) ? bq : (p==1 ? bk : bv);
    const float bscale = (p==0) ? LOG2E : 1.0f;
    #pragma unroll
    for (int nt=0;nt<4;nt++){
        const int hl = nt*16+m;
        const float bb = bp[hl]*bscale;
        #pragma unroll
        for (int r=0;r<4;r++){
            const int gr = r0 + wv*16 + quad*4 + r;   // D: row = quad*4+reg
            const float val = acc[nt][r] + bb;
            if (p<2){
                unsigned u = __float_as_uint(val);
                u16 hi = (u16)(u>>16);
                float hif = __uint_as_float(u & 0xFFFF0000u);
                u16 lo = rh_bf16(val - hif);
                u16* dh = (p==0) ? q_hi : k_hi;
                u16* dl = (p==0) ? q_lo : k_lo;
                dh[(size_t)gr*H + hl] = hi;
                dl[(size_t)gr*H + hl] = lo;
            } else {
                v_bf[(size_t)gr*H + hl] = rh_bf16(val);
            }
        }
    }
}

// ============================================================
// k2: v_bf [b][s][h] -> vt [b][h][s]  (LDS transpose, coalesced)
// ============================================================
__global__ __launch_bounds__(256) void vtrans_kernel(
    const u16* __restrict__ v_bf, u16* __restrict__ vt)
{
    __shared__ __align__(16) u16 tl[64][72];
    const int t = threadIdx.x;
    const int b = blockIdx.x >> 5, s0 = (blockIdx.x & 31)*64;
    {
        const int r = t>>2, c16 = (t&3)*16;
        const u16* src = v_bf + (size_t)(b*S + s0 + r)*H + c16;
        *(u16x8*)&tl[r][c16]   = *(const u16x8*)src;
        *(u16x8*)&tl[r][c16+8] = *(const u16x8*)(src+8);
    }
    __syncthreads();
    const int h = t>>2, s16 = (t&3)*16;
    u16 oa[16];
    #pragma unroll
    for (int j=0;j<16;j++) oa[j] = tl[s16+j][h];
    u16* dst = vt + (size_t)(b*H + h)*S + s0 + s16;
    *(u16x8*)dst     = *(u16x8*)&oa[0];
    *(u16x8*)(dst+8) = *(u16x8*)&oa[8];
}

// ============================================================
// k3: flash attention, fixed-max softmax (log2 domain), split-K.
// block = 256 thr (4 waves x 16 q-rows = 64 q-rows), TK=32/iter.
// K tiles LDS-split even/odd so B-frag rows are conflict-friendly;
// D-tile jt col c <-> key j0 + 2c + jt; P stored in that natural order.
// Writes partial acc[chunk] and l[chunk] (fixed max -> plain-add merge).
// ============================================================
__global__ __launch_bounds__(256) void attn_kernel(
    const u16* __restrict__ qh_g, const u16* __restrict__ ql_g,
    const u16* __restrict__ kh_g, const u16* __restrict__ kl_g,
    const u16* __restrict__ vt_g,
    float* __restrict__ accw, float* __restrict__ lw, int ksplit)
{
    __shared__ __align__(16) u16 khe[2][16][72];   // [jj&1][jj>>1][h]
    __shared__ __align__(16) u16 kle[2][16][72];
    __shared__ __align__(16) u16 vtl[64][40];      // [h][jj]
    __shared__ __align__(16) u16 pl[4][16][40];    // per-wave P [row][jj]

    const int t = threadIdx.x;
    const int wv = t>>6, lane = t&63, m = lane&15, quad = lane>>4;
    const int bid = blockIdx.x;
    const int qb = bid / ksplit, chunk = bid % ksplit;
    const int b = qb >> 5, s0 = (qb & 31)*64;
    const int ck = S / ksplit;
    const int j0base = chunk * ck;
    const int iters = ck / 32;

    // persistent q fragments (hi c0/c1, lo c0/c1)
    const u16* qr = qh_g + (size_t)(b*S + s0 + wv*16 + m)*H + quad*8;
    const u16* qrl = ql_g + (size_t)(b*S + s0 + wv*16 + m)*H + quad*8;
    const v8s qh0 = *(const v8s*)(qr),  qh1 = *(const v8s*)(qr+32);
    const v8s ql0 = *(const v8s*)(qrl), ql1 = *(const v8s*)(qrl+32);

    v4f oacc[4];
    #pragma unroll
    for (int nt=0;nt<4;nt++) oacc[nt] = (v4f){0.f,0.f,0.f,0.f};
    float lp[4] = {0.f,0.f,0.f,0.f};
    const v4f cinit = (v4f){CINIT,CINIT,CINIT,CINIT};

    // staging coords
    const int sj = t>>3, sh8 = (t&7)*8;   // K tiles: 32 rows x 64 h
    const u16* khs = kh_g + (size_t)(b*S + j0base + sj)*H + sh8;
    const u16* kls = kl_g + (size_t)(b*S + j0base + sj)*H + sh8;
    u16* khd = &khe[sj&1][sj>>1][sh8];
    u16* kld = &kle[sj&1][sj>>1][sh8];
    const int vh = t>>2, vj8 = (t&3)*8;   // vt tile: 64 h x 32 jj
    const u16* vts = vt_g + (size_t)(b*H + vh)*S + j0base + vj8;
    u16* vtd = &vtl[vh][vj8];

    for (int it=0; it<iters; ++it){
        __syncthreads();
        *(u16x8*)khd = *(const u16x8*)(khs + (size_t)it*32*H);
        *(u16x8*)kld = *(const u16x8*)(kls + (size_t)it*32*H);
        *(u16x8*)vtd = *(const u16x8*)(vts + it*32);
        __syncthreads();

        // ---- QK^T: 2 D-tiles x 6 MFMAs (3-term hi/lo), C-init = -m_fix ----
        v4f sc[2];
        #pragma unroll
        for (int jt=0;jt<2;jt++){
            const u16* kr  = &khe[jt][m][quad*8];
            const u16* krl = &kle[jt][m][quad*8];
            v8s b0 = *(const v8s*)kr,  b1 = *(const v8s*)(kr+32);
            v8s c0 = *(const v8s*)krl, c1 = *(const v8s*)(krl+32);
            v4f d = cinit;
            d = MFMA(qh0,b0,d); d = MFMA(qh1,b1,d);
            d = MFMA(ql0,b0,d); d = MFMA(ql1,b1,d);
            d = MFMA(qh0,c0,d); d = MFMA(qh1,c1,d);
            sc[jt] = d;
        }

        // ---- P = exp2(s'), accumulate l, pack to bf16 pairs in LDS ----
        #pragma unroll
        for (int r=0;r<4;r++){
            float p0 = exp2f(sc[0][r]);   // key j0 + 2m
            float p1 = exp2f(sc[1][r]);   // key j0 + 2m + 1
            lp[r] += p0 + p1;
            unsigned pk = ((__float_as_uint(p0)+0x8000u)>>16)
                        | ((__float_as_uint(p1)+0x8000u) & 0xFFFF0000u);
            *(unsigned*)&pl[wv][quad*4+r][2*m] = pk;
        }
        __syncthreads();   // P region is wave-local; barrier is conservative

        // ---- PV: A = P (LDS A-layout), B = v^T fragments ----
        v8s pa = *(const v8s*)&pl[wv][m][quad*8];
        #pragma unroll
        for (int nt=0;nt<4;nt++){
            v8s vb = *(const v8s*)&vtl[nt*16+m][quad*8];
            oacc[nt] = MFMA(pa, vb, oacc[nt]);
        }
    }

    // ---- epilogue: reduce l across 16 cols, write partials ----
    #pragma unroll
    for (int r=0;r<4;r++){
        float v = lp[r];
        v += __shfl_xor(v,1); v += __shfl_xor(v,2);
        v += __shfl_xor(v,4); v += __shfl_xor(v,8);
        lp[r] = v;
    }
    const int growb = b*S + s0 + wv*16;
    if (m==0){
        float4 lv; lv.x=lp[0]; lv.y=lp[1]; lv.z=lp[2]; lv.w=lp[3];
        *(float4*)(lw + (size_t)chunk*BS + growb + quad*4) = lv;
    }
    float* ab = accw + ((size_t)chunk*BS + growb)*H;
    #pragma unroll
    for (int nt=0;nt<4;nt++){
        #pragma unroll
        for (int r=0;r<4;r++)
            ab[(size_t)(quad*4+r)*H + nt*16 + m] = oacc[nt][r];
    }
}

// ============================================================
// k4: merge split-K partials: out = sum_c acc / sum_c l
// ============================================================
__global__ __launch_bounds__(256) void merge_kernel(
    const float* __restrict__ accw, const float* __restrict__ lw,
    float* __restrict__ out, int ksplit)
{
    const int idx = blockIdx.x*256 + threadIdx.x;
    const int row = idx >> 4, h4 = (idx & 15)*4;
    float4 a = {0.f,0.f,0.f,0.f};
    float ls = 0.f;
    for (int c=0;c<ksplit;c++){
        const float4 t4 = *(const float4*)(accw + ((size_t)c*BS + row)*H + h4);
        a.x+=t4.x; a.y+=t4.y; a.z+=t4.z; a.w+=t4.w;
        ls += lw[(size_t)c*BS + row];
    }
    const float inv = __builtin_amdgcn_rcpf(ls);
    float4 o; o.x=a.x*inv; o.y=a.y*inv; o.z=a.z*inv; o.w=a.w*inv;
    *(float4*)(out + (size_t)row*H + h4) = o;
}

// ============================================================
extern "C" void kernel_launch(void* const* d_in, const int* in_sizes, int n_in,
                              void* d_out, int out_size, void* d_ws, size_t ws_size,
                              hipStream_t stream) {
    const float* query = (const float*)d_in[0];
    const float* key_  = (const float*)d_in[1];
    const float* value = (const float*)d_in[2];
    const float* Wq    = (const float*)d_in[3];
    const float* bq    = (const float*)d_in[4];
    const float* Wk    = (const float*)d_in[5];
    const float* bk    = (const float*)d_in[6];
    const float* Wv    = (const float*)d_in[7];
    const float* bv    = (const float*)d_in[8];
    float* out = (float*)d_out;

    char* base = (char*)d_ws;
    size_t off = 0;
    u16* Wt_hi = (u16*)(base + off); off += (size_t)3*64*E*2;
    u16* Wt_lo = (u16*)(base + off); off += (size_t)3*64*E*2;
    u16* q_hi  = (u16*)(base + off); off += (size_t)BS*H*2;
    u16* q_lo  = (u16*)(base + off); off += (size_t)BS*H*2;
    u16* k_hi  = (u16*)(base + off); off += (size_t)BS*H*2;
    u16* k_lo  = (u16*)(base + off); off += (size_t)BS*H*2;
    u16* v_bf  = (u16*)(base + off); off += (size_t)BS*H*2;
    u16* vt    = (u16*)(base + off); off += (size_t)BS*H*2;
    const size_t fixed = off;
    const size_t CH = (size_t)BS*H*4 + (size_t)BS*4;  // acc + l per chunk

    int K = 1;
    if      (ws_size >= fixed + 8*CH) K = 8;
    else if (ws_size >= fixed + 4*CH) K = 4;
    else if (ws_size >= fixed + 2*CH) K = 2;

    float* lw   = (float*)(base + fixed);
    float* accw = (float*)(base + fixed + (size_t)K*BS*4);

    wsetup_kernel<<<48, 256, 0, stream>>>(Wq, Wk, Wv, Wt_hi, Wt_lo);
    proj_kernel<<<768, 128, 0, stream>>>(query, key_, value, Wt_hi, Wt_lo,
                                         bq, bk, bv, q_hi, q_lo, k_hi, k_lo, v_bf);
    vtrans_kernel<<<128, 256, 0, stream>>>(v_bf, vt);
    attn_kernel<<<128*K, 256, 0, stream>>>(q_hi, q_lo, k_hi, k_lo, vt, accw, lw, K);
    merge_kernel<<<512, 256, 0, stream>>>(accw, lw, out, K);
}